// Round 5
// baseline (766.310 us; speedup 1.0000x reference)
//
#include <hip/hip_runtime.h>
#include <math.h>

// ---------------------------------------------------------------------------
// SwinTransformerBlock3D  (B=2, D=16, H=56, W=56, C=256, heads=8, ws=4, ss=2)
// f32 in / f32 out. M = 100352 rows, 1568 windows. 7 launches:
//   transpose_all -> ln1+roll+partition -> qkv GEMM -> attention
//   -> proj GEMM(+reverse+roll+resid -> d_out f32) -> ln2 -> fused MLP
// Round 2: XCD swizzle cut FETCH 4x but slowed fc1 (latency-bound). Reverted.
// Round 3: proj_ln2 fat-acc fusion +45us. Reverted. GELU divide fixed w/ rcp.
// Round 4 (WIN, 734->706): LDS-bounce epilogue, coalesced dwordx4 stores.
// Round 5: fuse fc1+GELU+fc2 into mlp_k. h1 (205MB bf16) was written to HBM
//   by fc1 and read back by fc2 — 410MB of 767MB combined traffic. Fused:
//   h1 chunk (64x128) lives in LDS; W1/W2 are L2-hot; out-acc 64x64/wave.
//   fc1+fc2 = 271us -> predicted 90-150us.
// GEMM: BK=64, global_load_lds width=16 + XOR swizzle (m97 structure).
// ---------------------------------------------------------------------------

using f32x4  = __attribute__((ext_vector_type(4))) float;
using bf16x8 = __attribute__((ext_vector_type(8))) short;

#define MFMA16 __builtin_amdgcn_mfma_f32_16x16x32_bf16

__device__ __forceinline__ short f2bf(float f) {
  unsigned u = __builtin_bit_cast(unsigned, f);
  u += 0x7fffu + ((u >> 16) & 1u);          // RNE
  return (short)(u >> 16);
}

__device__ __forceinline__ float gelu_f(float v) {
  // gelu = v * e/(e+1) = v - v*rcp(e+1),  e = exp(2*0.79788456*(v+0.044715 v^3))
  const float u = 1.5957691216057308f * v * (1.f + 0.044715f * v * v);
  const float e = __expf(u);
  return v - v * __builtin_amdgcn_rcpf(e + 1.f);
}

#define GLDS16(g, l) __builtin_amdgcn_global_load_lds(                        \
    (__attribute__((address_space(1))) void*)(g),                             \
    (__attribute__((address_space(3))) void*)(l), 16, 0, 0)

// ---------------------------------------------------------------------------
// all four weight transposes in one launch: [K][N] f32 -> [N][K] bf16
__global__ void transpose_all_k(const float* __restrict__ qkv_w,
                                const float* __restrict__ proj_w,
                                const float* __restrict__ fc1_w,
                                const float* __restrict__ fc2_w,
                                short* __restrict__ o_qkv,
                                short* __restrict__ o_proj,
                                short* __restrict__ o_fc1,
                                short* __restrict__ o_fc2) {
  int bid = blockIdx.x;
  const float* in; short* out; int K, N;
  if (bid < 768)       { in = qkv_w;  out = o_qkv;  K = 256;  N = 768; }
  else if (bid < 1024) { in = proj_w; out = o_proj; K = 256;  N = 256;  bid -= 768; }
  else if (bid < 2048) { in = fc1_w;  out = o_fc1;  K = 256;  N = 1024; bid -= 1024; }
  else                 { in = fc2_w;  out = o_fc2;  K = 1024; N = 256;  bid -= 2048; }
  const int idx = bid * 256 + threadIdx.x;
  const int k = idx / N, n = idx % N;
  out[(size_t)n * K + k] = f2bf(in[idx]);
}

// ---------------------------------------------------------------------------
// LN1 + roll(-2) + window partition.  One wave per output row.
__global__ __launch_bounds__(256) void ln1_part_k(
    const float* __restrict__ x, const float* __restrict__ g,
    const float* __restrict__ bta, short* __restrict__ xw) {
  const int wave = threadIdx.x >> 6, lane = threadIdx.x & 63;
  const int row = blockIdx.x * 4 + wave;
  const int win = row >> 6, tok = row & 63;
  const int b = win / 784, wi = win % 784;
  const int wd = wi / 196, wh = (wi / 14) % 14, ww = wi % 14;
  const int tz = tok >> 4, ty = (tok >> 2) & 3, tx = tok & 3;
  const int gd = (wd * 4 + tz + 2) & 15;
  int gh = wh * 4 + ty + 2; if (gh >= 56) gh -= 56;
  int gw = ww * 4 + tx + 2; if (gw >= 56) gw -= 56;
  const size_t src = ((((size_t)b * 16 + gd) * 56 + gh) * 56 + gw) * 256;
  const float4 v = ((const float4*)(x + src))[lane];
  float s = v.x + v.y + v.z + v.w;
#pragma unroll
  for (int m = 1; m < 64; m <<= 1) s += __shfl_xor(s, m);
  const float mean = s * (1.f / 256.f);
  const float dx = v.x - mean, dy = v.y - mean, dz = v.z - mean, dw = v.w - mean;
  float q = dx * dx + dy * dy + dz * dz + dw * dw;
#pragma unroll
  for (int m = 1; m < 64; m <<= 1) q += __shfl_xor(q, m);
  const float rstd = rsqrtf(q * (1.f / 256.f) + 1e-5f);
  const float4 gg = ((const float4*)g)[lane];
  const float4 bb = ((const float4*)bta)[lane];
  short4 o;
  o.x = f2bf(dx * rstd * gg.x + bb.x);
  o.y = f2bf(dy * rstd * gg.y + bb.y);
  o.z = f2bf(dz * rstd * gg.z + bb.z);
  o.w = f2bf(dw * rstd * gg.w + bb.w);
  *(short4*)(xw + (size_t)row * 256 + lane * 4) = o;
}

// LN2: reads f32 x1 (== d_out), writes bf16 yn
__global__ __launch_bounds__(256) void ln2_k(
    const float* __restrict__ x1, const float* __restrict__ g,
    const float* __restrict__ bta, short* __restrict__ yn) {
  const int wave = threadIdx.x >> 6, lane = threadIdx.x & 63;
  const int row = blockIdx.x * 4 + wave;
  const float4 v = ((const float4*)(x1 + (size_t)row * 256))[lane];
  float s = v.x + v.y + v.z + v.w;
#pragma unroll
  for (int m = 1; m < 64; m <<= 1) s += __shfl_xor(s, m);
  const float mean = s * (1.f / 256.f);
  const float dx = v.x - mean, dy = v.y - mean, dz = v.z - mean, dw = v.w - mean;
  float q = dx * dx + dy * dy + dz * dz + dw * dw;
#pragma unroll
  for (int m = 1; m < 64; m <<= 1) q += __shfl_xor(q, m);
  const float rstd = rsqrtf(q * (1.f / 256.f) + 1e-5f);
  const float4 gg = ((const float4*)g)[lane];
  const float4 bb = ((const float4*)bta)[lane];
  short4 o;
  o.x = f2bf(dx * rstd * gg.x + bb.x);
  o.y = f2bf(dy * rstd * gg.y + bb.y);
  o.z = f2bf(dz * rstd * gg.z + bb.z);
  o.w = f2bf(dw * rstd * gg.w + bb.w);
  *(short4*)(yn + (size_t)row * 256 + lane * 4) = o;
}

// ---------------------------------------------------------------------------
// bf16 MFMA GEMM: C[M,N] = A[M,K] * Bt[N,K]^T + bias. 128x128 tile, BK=64,
// global_load_lds width=16 + XOR swizzle (m97 structure).
// Epilogue: LDS-bounce (reuse As/Bs region) -> coalesced 16B/lane stores.
// EPI: 0=bf16 store, 2=f32 swin-reverse+roll+resid(x f32) scatter -> d_out
template <int EPI>
__global__ __launch_bounds__(256) void gemm_k(
    const short* __restrict__ A, const short* __restrict__ Bt,
    const float* __restrict__ bias, const float* __restrict__ resid,
    void* __restrict__ OutP, int N, int K) {
  __shared__ short SMEM[16384];               // 32 KB: As | Bs, reused as Cs
  short* As = SMEM;
  short* Bs = SMEM + 8192;
  const int tid = threadIdx.x;
  const int wave = tid >> 6, lane = tid & 63;
  const int quad = lane >> 4, l15 = lane & 15;
  const int m0 = blockIdx.y * 128;
  const int n0 = blockIdx.x * 128;
  const int wm = (wave >> 1) * 64, wn = (wave & 1) * 64;

  f32x4 acc[4][4] = {};

  for (int k0 = 0; k0 < K; k0 += 64) {
    __syncthreads();
#pragma unroll
    for (int i = 0; i < 4; ++i) {
      const int p = wave * 256 + i * 64 + lane;
      const int row = p >> 3;
      const int c = (p & 7) ^ (row & 7);                 // XOR swizzle
      GLDS16(A  + (size_t)(m0 + row) * K + (k0 + c * 8),
             As + (size_t)(wave * 256 + i * 64) * 8);
      GLDS16(Bt + (size_t)(n0 + row) * K + (k0 + c * 8),
             Bs + (size_t)(wave * 256 + i * 64) * 8);
    }
    __syncthreads();
#pragma unroll
    for (int ks = 0; ks < 2; ++ks) {
      bf16x8 af[4], bfr[4];
#pragma unroll
      for (int t = 0; t < 4; ++t) {
        const int ra = wm + t * 16 + l15;
        const int ca = (ks * 4 + quad) ^ (ra & 7);
        af[t] = *(const bf16x8*)(As + ra * 64 + ca * 8);
        const int rb = wn + t * 16 + l15;
        const int cb = (ks * 4 + quad) ^ (rb & 7);
        bfr[t] = *(const bf16x8*)(Bs + rb * 64 + cb * 8);
      }
#pragma unroll
      for (int mt = 0; mt < 4; ++mt)
#pragma unroll
        for (int nt = 0; nt < 4; ++nt)
          acc[mt][nt] = MFMA16(af[mt], bfr[nt], acc[mt][nt], 0, 0, 0);
    }
  }

  // --- LDS-bounce epilogue.  acc layout: row=quad*4+reg, col=l15 [m89/m91].
  __syncthreads();                            // all K-loop ds_reads complete
  if constexpr (EPI == 0) {
    // bf16 C tile [128][128] with 16B-chunk XOR swizzle (chunk ^= row&7)
#pragma unroll
    for (int nt = 0; nt < 4; ++nt) {
      const int col = wn + nt * 16 + l15;
      const float bv = bias[n0 + col];
#pragma unroll
      for (int mt = 0; mt < 4; ++mt)
#pragma unroll
        for (int reg = 0; reg < 4; ++reg) {
          const int row = wm + mt * 16 + quad * 4 + reg;
          const int byte = (row << 8) | ((col << 1) ^ ((row & 7) << 4));
          *(short*)((char*)SMEM + byte) = f2bf(acc[mt][nt][reg] + bv);
        }
    }
    __syncthreads();
    short* out = (short*)OutP;
#pragma unroll
    for (int i = 0; i < 8; ++i) {
      const int off = i * 4096 + tid * 16;    // logical byte in [128][256B]
      const int row = off >> 8;
      const bf16x8 val =
          *(const bf16x8*)((char*)SMEM + (off ^ ((row & 7) << 4)));
      *(bf16x8*)(out + (size_t)(m0 + row) * N + n0 + ((off & 255) >> 1)) = val;
    }
  } else {
    // f32 path in two 64-row halves (32 KB each): Cs_f32[64][128]
    float* out = (float*)OutP;
#pragma unroll
    for (int hh = 0; hh < 2; ++hh) {
      if (hh) __syncthreads();                // protect previous read phase
      if (wm == hh * 64) {
#pragma unroll
        for (int nt = 0; nt < 4; ++nt) {
          const int col = wn + nt * 16 + l15;
          const float bv = bias[n0 + col];
#pragma unroll
          for (int mt = 0; mt < 4; ++mt)
#pragma unroll
            for (int reg = 0; reg < 4; ++reg) {
              const int rloc = mt * 16 + quad * 4 + reg;
              const int byte = (rloc << 9) | ((col << 2) ^ ((rloc & 7) << 4));
              *(float*)((char*)SMEM + byte) = acc[mt][nt][reg] + bv;
            }
        }
      }
      __syncthreads();
#pragma unroll
      for (int i = 0; i < 8; ++i) {
        const int off = i * 4096 + tid * 16;  // logical byte in [64][512B]
        const int rloc = off >> 9;
        f32x4 val = *(const f32x4*)((char*)SMEM + (off ^ ((rloc & 7) << 4)));
        const int colf = (off & 511) >> 2;
        const int grow = m0 + hh * 64 + rloc;
        const int win = grow >> 6, tok = grow & 63;
        const int b = win / 784, wi = win % 784;
        const int wd = wi / 196, wh = (wi / 14) % 14, ww = wi % 14;
        const int tz = tok >> 4, ty = (tok >> 2) & 3, tx = tok & 3;
        const int gd = (wd * 4 + tz + 2) & 15;
        int gh = wh * 4 + ty + 2; if (gh >= 56) gh -= 56;
        int gw = ww * 4 + tx + 2; if (gw >= 56) gw -= 56;
        const size_t dst = ((((size_t)b * 16 + gd) * 56 + gh) * 56 + gw) * 256
                           + n0 + colf;
        const f32x4 r = *(const f32x4*)(resid + dst);
        val = val + r;
        *(f32x4*)(out + dst) = val;
      }
    }
  }
}

// ---------------------------------------------------------------------------
// Fused MLP: out = x1 + GELU(yn @ W1 + b1) @ W2 + b2.
// Block = 64 rows, 4 waves. 8 chunks of 128 h-cols; h1 chunk lives in LDS.
// Stage-1 wave grid 2x2 (wave owns 32x64 of H chunk, hacc[2][4]).
// Stage-2 wave owns 64 rows x 64 out-cols (oacc[4][4]); W2 frags from L2.
// LDS 40KB: As[64][64] | Bs[128][64] | Hs[64][128]; epilogue Cs[32][256] f32.
__global__ __launch_bounds__(256) void mlp_k(
    const short* __restrict__ A,      // yn [M][256] bf16
    const short* __restrict__ W1,     // wt_fc1 [1024][256] bf16
    const short* __restrict__ W2,     // wt_fc2 [256][1024] bf16
    const float* __restrict__ b1, const float* __restrict__ b2,
    const float* __restrict__ resid,  // x1 f32 [M][256]
    float* __restrict__ out) {
  __shared__ short SMEM[20480];       // 40 KB
  short* As = SMEM;                   // [64][64]   8 KB
  short* Bs = SMEM + 4096;            // [128][64] 16 KB
  short* Hs = SMEM + 12288;           // [64][128] 16 KB (16B-chunk XOR swz)
  const int tid = threadIdx.x;
  const int wave = tid >> 6, lane = tid & 63;
  const int quad = lane >> 4, l15 = lane & 15;
  const int wr = wave >> 1, wc = wave & 1;
  const int m0 = blockIdx.x * 64;

  f32x4 oacc[4][4] = {};

  for (int j = 0; j < 8; ++j) {
    f32x4 hacc[2][4] = {};
    for (int k0 = 0; k0 < 256; k0 += 64) {
      __syncthreads();
#pragma unroll
      for (int i = 0; i < 2; ++i) {                 // As: 512 chunks
        const int p = i * 256 + tid;
        const int row = p >> 3;
        const int c = (p & 7) ^ (row & 7);
        GLDS16(A + (size_t)(m0 + row) * 256 + (k0 + c * 8),
               As + (size_t)p * 8);
      }
#pragma unroll
      for (int i = 0; i < 4; ++i) {                 // Bs: 1024 chunks
        const int p = i * 256 + tid;
        const int row = p >> 3;
        const int c = (p & 7) ^ (row & 7);
        GLDS16(W1 + (size_t)(j * 128 + row) * 256 + (k0 + c * 8),
               Bs + (size_t)p * 8);
      }
      __syncthreads();
#pragma unroll
      for (int ks = 0; ks < 2; ++ks) {
        bf16x8 af[2], bfr[4];
#pragma unroll
        for (int mt = 0; mt < 2; ++mt) {
          const int ra = wr * 32 + mt * 16 + l15;
          const int ca = (ks * 4 + quad) ^ (ra & 7);
          af[mt] = *(const bf16x8*)(As + ra * 64 + ca * 8);
        }
#pragma unroll
        for (int nt = 0; nt < 4; ++nt) {
          const int rb = wc * 64 + nt * 16 + l15;
          const int cb = (ks * 4 + quad) ^ (rb & 7);
          bfr[nt] = *(const bf16x8*)(Bs + rb * 64 + cb * 8);
        }
#pragma unroll
        for (int mt = 0; mt < 2; ++mt)
#pragma unroll
          for (int nt = 0; nt < 4; ++nt)
            hacc[mt][nt] = MFMA16(af[mt], bfr[nt], hacc[mt][nt], 0, 0, 0);
      }
    }
    // GELU + pack -> Hs (write chunk c at c ^ (token&7))
#pragma unroll
    for (int nt = 0; nt < 4; ++nt) {
      const int h = wc * 64 + nt * 16 + l15;
      const float bv = b1[j * 128 + h];
      const int hc = h >> 3, hsub = (h & 7) * 2;
#pragma unroll
      for (int mt = 0; mt < 2; ++mt)
#pragma unroll
        for (int reg = 0; reg < 4; ++reg) {
          const int t = wr * 32 + mt * 16 + quad * 4 + reg;
          const float v = gelu_f(hacc[mt][nt][reg] + bv);
          const int byte = t * 256 + ((hc ^ (t & 7)) << 4) + hsub;
          *(short*)((char*)Hs + byte) = f2bf(v);
        }
    }
    // W2 fragments for this chunk (L2-hot, 16 x 16B per lane)
    bf16x8 bf2[4][4];
#pragma unroll
    for (int kk = 0; kk < 4; ++kk)
#pragma unroll
      for (int nt = 0; nt < 4; ++nt) {
        const int n = wave * 64 + nt * 16 + l15;
        bf2[kk][nt] = *(const bf16x8*)(
            W2 + (size_t)n * 1024 + j * 128 + kk * 32 + quad * 8);
      }
    __syncthreads();                                 // Hs visible
#pragma unroll
    for (int kk = 0; kk < 4; ++kk) {
      bf16x8 af2[4];
#pragma unroll
      for (int mt = 0; mt < 4; ++mt) {
        const int t = mt * 16 + l15;
        const int c = kk * 4 + quad;
        af2[mt] = *(const bf16x8*)((char*)Hs + t * 256 + ((c ^ (t & 7)) << 4));
      }
#pragma unroll
      for (int mt = 0; mt < 4; ++mt)
#pragma unroll
        for (int nt = 0; nt < 4; ++nt)
          oacc[mt][nt] = MFMA16(af2[mt], bf2[kk][nt], oacc[mt][nt], 0, 0, 0);
    }
  }

  // epilogue: two 32-row halves through Cs f32 [32][256] (32 KB of SMEM)
#pragma unroll
  for (int hh = 0; hh < 2; ++hh) {
    __syncthreads();                                 // prior LDS readers done
#pragma unroll
    for (int mi = 0; mi < 2; ++mi) {
      const int mt = hh * 2 + mi;
#pragma unroll
      for (int nt = 0; nt < 4; ++nt) {
        const int col = wave * 64 + nt * 16 + l15;
        const float bv = b2[col];
#pragma unroll
        for (int reg = 0; reg < 4; ++reg) {
          const int rl = mi * 16 + quad * 4 + reg;   // 0..31 in half
          const int byte =
              rl * 1024 + (((col >> 2) ^ (rl & 7)) << 4) + (col & 3) * 4;
          *(float*)((char*)SMEM + byte) = oacc[mt][nt][reg] + bv;
        }
      }
    }
    __syncthreads();
#pragma unroll
    for (int i = 0; i < 8; ++i) {
      const int off = i * 4096 + tid * 16;           // [32][1024B]
      const int rloc = off >> 10;
      const int win = off & 1023;
      const int byte = rloc * 1024 + (((win >> 4) ^ (rloc & 7)) << 4);
      f32x4 v = *(const f32x4*)((char*)SMEM + byte);
      const size_t dst = (size_t)(m0 + hh * 32 + rloc) * 256 + (win >> 2);
      const f32x4 r = *(const f32x4*)(resid + dst);
      v = v + r;
      *(f32x4*)(out + dst) = v;
    }
  }
}

// ---------------------------------------------------------------------------
// Windowed attention. grid = 1568*2 blocks; 4 waves, 1 head/wave.
__global__ __launch_bounds__(256) void attn_k(
    const short* __restrict__ qkv, const float* __restrict__ rpb,
    short* __restrict__ aout) {
  __shared__ short Plds[4 * 64 * 80];
  const int tid = threadIdx.x;
  const int wave = tid >> 6, lane = tid & 63;
  const int quad = lane >> 4, l15 = lane & 15;
  const int win = blockIdx.x >> 1;
  const int h = ((blockIdx.x & 1) << 2) + wave;
  const int wi = win % 784;
  const int wd = wi / 196, wh = (wi / 14) % 14, ww = wi % 14;
  const short* base = qkv + (size_t)win * (64 * 768);

  bf16x8 qf[4], kf[4];
#pragma unroll
  for (int t = 0; t < 4; ++t) {
    const short* qp = base + (size_t)(t * 16 + l15) * 768 + h * 32 + quad * 8;
    qf[t] = *(const bf16x8*)qp;
    kf[t] = *(const bf16x8*)(qp + 256);
  }
  f32x4 S[4][4] = {};
#pragma unroll
  for (int mt = 0; mt < 4; ++mt)
#pragma unroll
    for (int nt = 0; nt < 4; ++nt)
      S[mt][nt] = MFMA16(qf[mt], kf[nt], S[mt][nt], 0, 0, 0);

  const bool bd = (wd == 3), bh = (wh == 13), bw = (ww == 13);
  const int yc = l15 >> 2, xc = l15 & 3;
  int labc[4];
#pragma unroll
  for (int nt = 0; nt < 4; ++nt) {
    const int rd = bd ? (nt < 2 ? 1 : 2) : 0;
    const int rh = bh ? (yc < 2 ? 1 : 2) : 0;
    const int rw = bw ? (xc < 2 ? 1 : 2) : 0;
    labc[nt] = rd * 9 + rh * 3 + rw;
  }
  const float scale = 0.17677669529663687f;   // 32^-0.5
#pragma unroll
  for (int mt = 0; mt < 4; ++mt) {
    const int rdr = bd ? (mt < 2 ? 1 : 2) : 0;
    const int rhr = bh ? (quad < 2 ? 1 : 2) : 0;
#pragma unroll
    for (int reg = 0; reg < 4; ++reg) {
      const int rwr = bw ? (reg < 2 ? 1 : 2) : 0;
      const int labr = rdr * 9 + rhr * 3 + rwr;
      float sc[4];
#pragma unroll
      for (int nt = 0; nt < 4; ++nt) {
        const int rpi = (mt - nt + 3) * 49 + (quad - yc + 3) * 7 + (reg - xc + 3);
        const float bias = rpb[rpi * 8 + h];
        const float mv = (labr == labc[nt]) ? 0.f : -100.f;
        sc[nt] = S[mt][nt][reg] * scale + bias + mv;
      }
      float mx = fmaxf(fmaxf(sc[0], sc[1]), fmaxf(sc[2], sc[3]));
      mx = fmaxf(mx, __shfl_xor(mx, 1));
      mx = fmaxf(mx, __shfl_xor(mx, 2));
      mx = fmaxf(mx, __shfl_xor(mx, 4));
      mx = fmaxf(mx, __shfl_xor(mx, 8));
      float p[4], sum = 0.f;
#pragma unroll
      for (int nt = 0; nt < 4; ++nt) { p[nt] = __expf(sc[nt] - mx); sum += p[nt]; }
      sum += __shfl_xor(sum, 1);
      sum += __shfl_xor(sum, 2);
      sum += __shfl_xor(sum, 4);
      sum += __shfl_xor(sum, 8);
      const float inv = 1.f / sum;
      const int r = mt * 16 + quad * 4 + reg;
#pragma unroll
      for (int nt = 0; nt < 4; ++nt)
        Plds[(wave * 64 + r) * 80 + nt * 16 + l15] = f2bf(p[nt] * inv);
    }
  }

  bf16x8 vf[2][2];
#pragma unroll
  for (int kt = 0; kt < 2; ++kt)
#pragma unroll
    for (int n2 = 0; n2 < 2; ++n2)
#pragma unroll
      for (int j = 0; j < 8; ++j)
        vf[kt][n2][j] =
            base[(size_t)(kt * 32 + quad * 8 + j) * 768 + 512 + h * 32 + n2 * 16 + l15];

  f32x4 O[4][2] = {};
#pragma unroll
  for (int mt = 0; mt < 4; ++mt) {
    const short* pr = &Plds[(wave * 64 + mt * 16 + l15) * 80 + quad * 8];
    const bf16x8 pa0 = *(const bf16x8*)pr;
    const bf16x8 pa1 = *(const bf16x8*)(pr + 32);
#pragma unroll
    for (int n2 = 0; n2 < 2; ++n2) {
      O[mt][n2] = MFMA16(pa0, vf[0][n2], O[mt][n2], 0, 0, 0);
      O[mt][n2] = MFMA16(pa1, vf[1][n2], O[mt][n2], 0, 0, 0);
    }
  }
#pragma unroll
  for (int mt = 0; mt < 4; ++mt)
#pragma unroll
    for (int n2 = 0; n2 < 2; ++n2)
#pragma unroll
      for (int reg = 0; reg < 4; ++reg) {
        const int tok = mt * 16 + quad * 4 + reg;
        aout[((size_t)win * 64 + tok) * 256 + h * 32 + n2 * 16 + l15] =
            f2bf(O[mt][n2][reg]);
      }
}

// ---------------------------------------------------------------------------
extern "C" void kernel_launch(void* const* d_in, const int* in_sizes, int n_in,
                              void* d_out, int out_size, void* d_ws,
                              size_t ws_size, hipStream_t stream) {
  const float* x      = (const float*)d_in[0];
  const float* n1g    = (const float*)d_in[1];
  const float* n1b    = (const float*)d_in[2];
  const float* qkv_w  = (const float*)d_in[3];
  const float* qkv_b  = (const float*)d_in[4];
  const float* proj_w = (const float*)d_in[5];
  const float* proj_b = (const float*)d_in[6];
  const float* rpb    = (const float*)d_in[7];
  const float* n2g    = (const float*)d_in[8];
  const float* n2b    = (const float*)d_in[9];
  const float* fc1_w  = (const float*)d_in[10];
  const float* fc1_b  = (const float*)d_in[11];
  const float* fc2_w  = (const float*)d_in[12];
  const float* fc2_b  = (const float*)d_in[13];

  char* ws = (char*)d_ws;
  short* wt_qkv  = (short*)(ws + 0);          //     393,216 B
  short* wt_proj = (short*)(ws + 393216);     //     131,072 B
  short* wt_fc1  = (short*)(ws + 524288);     //     524,288 B
  short* wt_fc2  = (short*)(ws + 1048576);    //     524,288 B
  short* bufS    = (short*)(ws + 1572864);    //  51,380,224 B (xw/ao/yn)
  short* bufL    = (short*)(ws + 52953088);   // 205,520,896 B (qkv)
  float* x1      = (float*)d_out;             // x1 lives in d_out (f32)

  transpose_all_k<<<3072, 256, 0, stream>>>(qkv_w, proj_w, fc1_w, fc2_w,
                                            wt_qkv, wt_proj, wt_fc1, wt_fc2);
  ln1_part_k<<<25088, 256, 0, stream>>>(x, n1g, n1b, bufS);
  gemm_k<0><<<dim3(6, 784), 256, 0, stream>>>(bufS, wt_qkv, qkv_b, nullptr,
                                              bufL, 768, 256);
  attn_k<<<3136, 256, 0, stream>>>(bufL, rpb, bufS);
  gemm_k<2><<<dim3(2, 784), 256, 0, stream>>>(bufS, wt_proj, proj_b, x,
                                              x1, 256, 256);
  ln2_k<<<25088, 256, 0, stream>>>(x1, n2g, n2b, bufS);
  mlp_k<<<1568, 256, 0, stream>>>(bufS, wt_fc1, wt_fc2, fc1_b, fc2_b,
                                  x1, x1);
}

// Round 6
// 666.818 us; speedup vs baseline: 1.1492x; 1.1492x over previous
//
#include <hip/hip_runtime.h>
#include <math.h>

// ---------------------------------------------------------------------------
// SwinTransformerBlock3D  (B=2, D=16, H=56, W=56, C=256, heads=8, ws=4, ss=2)
// f32 in / f32 out. M = 100352 rows, 1568 windows. 8 launches:
//   transpose_all -> ln1+roll+partition -> qkv GEMM -> attention
//   -> proj GEMM(+reverse+roll+resid -> d_out f32) -> ln2
//   -> fc1 GEMM(+GELU) -> fc2 GEMM(+resid, in-place d_out)
// Round 2: XCD swizzle cut FETCH 4x but slowed fc1 (latency-bound). Reverted.
// Round 3: proj_ln2 fat-acc fusion +45us. Reverted. GELU divide -> rcp.
// Round 4 (WIN, 734->706): LDS-bounce epilogue, coalesced dwordx4 stores.
// Round 5: fused mlp_k = 332us vs 271 split (all pipes <20%; 76 lockstep
//   barrier drains/block, no overlap). REVERTED.
// Round 6: T3 2-phase double-buffered K-loop in gemm_k: stage tile t+1
//   BEFORE computing tile t, one barrier/tile (was: stage->drain->compute,
//   zero overlap -> 45% BW, MfmaUtil 16%). LDS 64KB (2x As/Bs), epilogue
//   reuses buffer 0. Round-4 epilogue kept verbatim.
// ---------------------------------------------------------------------------

using f32x4  = __attribute__((ext_vector_type(4))) float;
using bf16x8 = __attribute__((ext_vector_type(8))) short;

#define MFMA16 __builtin_amdgcn_mfma_f32_16x16x32_bf16

__device__ __forceinline__ short f2bf(float f) {
  unsigned u = __builtin_bit_cast(unsigned, f);
  u += 0x7fffu + ((u >> 16) & 1u);          // RNE
  return (short)(u >> 16);
}

__device__ __forceinline__ float gelu_f(float v) {
  // gelu = v * e/(e+1) = v - v*rcp(e+1),  e = exp(2*0.79788456*(v+0.044715 v^3))
  const float u = 1.5957691216057308f * v * (1.f + 0.044715f * v * v);
  const float e = __expf(u);
  return v - v * __builtin_amdgcn_rcpf(e + 1.f);
}

#define GLDS16(g, l) __builtin_amdgcn_global_load_lds(                        \
    (__attribute__((address_space(1))) void*)(g),                             \
    (__attribute__((address_space(3))) void*)(l), 16, 0, 0)

// ---------------------------------------------------------------------------
// all four weight transposes in one launch: [K][N] f32 -> [N][K] bf16
__global__ void transpose_all_k(const float* __restrict__ qkv_w,
                                const float* __restrict__ proj_w,
                                const float* __restrict__ fc1_w,
                                const float* __restrict__ fc2_w,
                                short* __restrict__ o_qkv,
                                short* __restrict__ o_proj,
                                short* __restrict__ o_fc1,
                                short* __restrict__ o_fc2) {
  int bid = blockIdx.x;
  const float* in; short* out; int K, N;
  if (bid < 768)       { in = qkv_w;  out = o_qkv;  K = 256;  N = 768; }
  else if (bid < 1024) { in = proj_w; out = o_proj; K = 256;  N = 256;  bid -= 768; }
  else if (bid < 2048) { in = fc1_w;  out = o_fc1;  K = 256;  N = 1024; bid -= 1024; }
  else                 { in = fc2_w;  out = o_fc2;  K = 1024; N = 256;  bid -= 2048; }
  const int idx = bid * 256 + threadIdx.x;
  const int k = idx / N, n = idx % N;
  out[(size_t)n * K + k] = f2bf(in[idx]);
}

// ---------------------------------------------------------------------------
// LN1 + roll(-2) + window partition.  One wave per output row.
__global__ __launch_bounds__(256) void ln1_part_k(
    const float* __restrict__ x, const float* __restrict__ g,
    const float* __restrict__ bta, short* __restrict__ xw) {
  const int wave = threadIdx.x >> 6, lane = threadIdx.x & 63;
  const int row = blockIdx.x * 4 + wave;
  const int win = row >> 6, tok = row & 63;
  const int b = win / 784, wi = win % 784;
  const int wd = wi / 196, wh = (wi / 14) % 14, ww = wi % 14;
  const int tz = tok >> 4, ty = (tok >> 2) & 3, tx = tok & 3;
  const int gd = (wd * 4 + tz + 2) & 15;
  int gh = wh * 4 + ty + 2; if (gh >= 56) gh -= 56;
  int gw = ww * 4 + tx + 2; if (gw >= 56) gw -= 56;
  const size_t src = ((((size_t)b * 16 + gd) * 56 + gh) * 56 + gw) * 256;
  const float4 v = ((const float4*)(x + src))[lane];
  float s = v.x + v.y + v.z + v.w;
#pragma unroll
  for (int m = 1; m < 64; m <<= 1) s += __shfl_xor(s, m);
  const float mean = s * (1.f / 256.f);
  const float dx = v.x - mean, dy = v.y - mean, dz = v.z - mean, dw = v.w - mean;
  float q = dx * dx + dy * dy + dz * dz + dw * dw;
#pragma unroll
  for (int m = 1; m < 64; m <<= 1) q += __shfl_xor(q, m);
  const float rstd = rsqrtf(q * (1.f / 256.f) + 1e-5f);
  const float4 gg = ((const float4*)g)[lane];
  const float4 bb = ((const float4*)bta)[lane];
  short4 o;
  o.x = f2bf(dx * rstd * gg.x + bb.x);
  o.y = f2bf(dy * rstd * gg.y + bb.y);
  o.z = f2bf(dz * rstd * gg.z + bb.z);
  o.w = f2bf(dw * rstd * gg.w + bb.w);
  *(short4*)(xw + (size_t)row * 256 + lane * 4) = o;
}

// LN2: reads f32 x1 (== d_out), writes bf16 yn
__global__ __launch_bounds__(256) void ln2_k(
    const float* __restrict__ x1, const float* __restrict__ g,
    const float* __restrict__ bta, short* __restrict__ yn) {
  const int wave = threadIdx.x >> 6, lane = threadIdx.x & 63;
  const int row = blockIdx.x * 4 + wave;
  const float4 v = ((const float4*)(x1 + (size_t)row * 256))[lane];
  float s = v.x + v.y + v.z + v.w;
#pragma unroll
  for (int m = 1; m < 64; m <<= 1) s += __shfl_xor(s, m);
  const float mean = s * (1.f / 256.f);
  const float dx = v.x - mean, dy = v.y - mean, dz = v.z - mean, dw = v.w - mean;
  float q = dx * dx + dy * dy + dz * dz + dw * dw;
#pragma unroll
  for (int m = 1; m < 64; m <<= 1) q += __shfl_xor(q, m);
  const float rstd = rsqrtf(q * (1.f / 256.f) + 1e-5f);
  const float4 gg = ((const float4*)g)[lane];
  const float4 bb = ((const float4*)bta)[lane];
  short4 o;
  o.x = f2bf(dx * rstd * gg.x + bb.x);
  o.y = f2bf(dy * rstd * gg.y + bb.y);
  o.z = f2bf(dz * rstd * gg.z + bb.z);
  o.w = f2bf(dw * rstd * gg.w + bb.w);
  *(short4*)(yn + (size_t)row * 256 + lane * 4) = o;
}

// ---------------------------------------------------------------------------
// bf16 MFMA GEMM: C[M,N] = A[M,K] * Bt[N,K]^T + bias. 128x128 tile, BK=64,
// global_load_lds width=16 + XOR swizzle. 2-phase double-buffered K-loop
// (T3 minimum): stage tile t+1 before compute of tile t; 1 barrier/tile.
// Epilogue: LDS-bounce (reuse buffer 0) -> coalesced 16B/lane stores.
// EPI: 0=bf16 store, 1=bf16 GELU store,
//      2=f32 swin-reverse+roll+resid(x f32) scatter -> d_out
//      3=f32 +resid(f32) -> d_out (linear rows)
template <int EPI>
__global__ __launch_bounds__(256) void gemm_k(
    const short* __restrict__ A, const short* __restrict__ Bt,
    const float* __restrict__ bias, const float* __restrict__ resid,
    void* __restrict__ OutP, int N, int K) {
  __shared__ short SMEM[32768];               // 64 KB: buf b at b*16384
  const int tid = threadIdx.x;
  const int wave = tid >> 6, lane = tid & 63;
  const int quad = lane >> 4, l15 = lane & 15;
  const int m0 = blockIdx.y * 128;
  const int n0 = blockIdx.x * 128;
  const int wm = (wave >> 1) * 64, wn = (wave & 1) * 64;

  f32x4 acc[4][4] = {};

  // stage K-tile at col kk into buffer b (As 16KB | Bs 16KB)
  auto stage = [&](int b, int kk) {
    short* Asb = SMEM + b * 16384;
    short* Bsb = Asb + 8192;
#pragma unroll
    for (int i = 0; i < 4; ++i) {
      const int p = wave * 256 + i * 64 + lane;
      const int row = p >> 3;
      const int c = (p & 7) ^ (row & 7);               // XOR swizzle
      GLDS16(A  + (size_t)(m0 + row) * K + (kk + c * 8),
             Asb + (size_t)(wave * 256 + i * 64) * 8);
      GLDS16(Bt + (size_t)(n0 + row) * K + (kk + c * 8),
             Bsb + (size_t)(wave * 256 + i * 64) * 8);
    }
  };
  auto compute = [&](int b) {
    const short* Asb = SMEM + b * 16384;
    const short* Bsb = Asb + 8192;
#pragma unroll
    for (int ks = 0; ks < 2; ++ks) {
      bf16x8 af[4], bfr[4];
#pragma unroll
      for (int t = 0; t < 4; ++t) {
        const int ra = wm + t * 16 + l15;
        const int ca = (ks * 4 + quad) ^ (ra & 7);
        af[t] = *(const bf16x8*)(Asb + ra * 64 + ca * 8);
        const int rb = wn + t * 16 + l15;
        const int cb = (ks * 4 + quad) ^ (rb & 7);
        bfr[t] = *(const bf16x8*)(Bsb + rb * 64 + cb * 8);
      }
#pragma unroll
      for (int mt = 0; mt < 4; ++mt)
#pragma unroll
        for (int nt = 0; nt < 4; ++nt)
          acc[mt][nt] = MFMA16(af[mt], bfr[nt], acc[mt][nt], 0, 0, 0);
    }
  };

  stage(0, 0);
  __syncthreads();                            // prologue drain
  int cur = 0;
  const int NT = K >> 6;
  for (int t = 0; t < NT - 1; ++t) {
    stage(cur ^ 1, (t + 1) * 64);             // issue next (overlaps compute)
    compute(cur);
    __syncthreads();                          // next tile ready; cur readers done
    cur ^= 1;
  }
  compute(cur);

  // --- LDS-bounce epilogue.  acc layout: row=quad*4+reg, col=l15 [m89/m91].
  __syncthreads();                            // all K-loop ds_reads complete
  if constexpr (EPI == 0 || EPI == 1) {
    // bf16 C tile [128][128] with 16B-chunk XOR swizzle (chunk ^= row&7)
#pragma unroll
    for (int nt = 0; nt < 4; ++nt) {
      const int col = wn + nt * 16 + l15;
      const float bv = bias[n0 + col];
#pragma unroll
      for (int mt = 0; mt < 4; ++mt)
#pragma unroll
        for (int reg = 0; reg < 4; ++reg) {
          const int row = wm + mt * 16 + quad * 4 + reg;
          float v = acc[mt][nt][reg] + bv;
          if constexpr (EPI == 1) v = gelu_f(v);
          const int byte = (row << 8) | ((col << 1) ^ ((row & 7) << 4));
          *(short*)((char*)SMEM + byte) = f2bf(v);
        }
    }
    __syncthreads();
    short* out = (short*)OutP;
#pragma unroll
    for (int i = 0; i < 8; ++i) {
      const int off = i * 4096 + tid * 16;    // logical byte in [128][256B]
      const int row = off >> 8;
      const bf16x8 val =
          *(const bf16x8*)((char*)SMEM + (off ^ ((row & 7) << 4)));
      *(bf16x8*)(out + (size_t)(m0 + row) * N + n0 + ((off & 255) >> 1)) = val;
    }
  } else {
    // f32 path in two 64-row halves (32 KB each): Cs_f32[64][128]
    float* out = (float*)OutP;
#pragma unroll
    for (int hh = 0; hh < 2; ++hh) {
      if (hh) __syncthreads();                // protect previous read phase
      if (wm == hh * 64) {
#pragma unroll
        for (int nt = 0; nt < 4; ++nt) {
          const int col = wn + nt * 16 + l15;
          const float bv = bias[n0 + col];
#pragma unroll
          for (int mt = 0; mt < 4; ++mt)
#pragma unroll
            for (int reg = 0; reg < 4; ++reg) {
              const int rloc = mt * 16 + quad * 4 + reg;
              const int byte = (rloc << 9) | ((col << 2) ^ ((rloc & 7) << 4));
              *(float*)((char*)SMEM + byte) = acc[mt][nt][reg] + bv;
            }
        }
      }
      __syncthreads();
#pragma unroll
      for (int i = 0; i < 8; ++i) {
        const int off = i * 4096 + tid * 16;  // logical byte in [64][512B]
        const int rloc = off >> 9;
        f32x4 val = *(const f32x4*)((char*)SMEM + (off ^ ((rloc & 7) << 4)));
        const int colf = (off & 511) >> 2;
        const int grow = m0 + hh * 64 + rloc;
        size_t dst;
        if constexpr (EPI == 2) {
          const int win = grow >> 6, tok = grow & 63;
          const int b = win / 784, wi = win % 784;
          const int wd = wi / 196, wh = (wi / 14) % 14, ww = wi % 14;
          const int tz = tok >> 4, ty = (tok >> 2) & 3, tx = tok & 3;
          const int gd = (wd * 4 + tz + 2) & 15;
          int gh = wh * 4 + ty + 2; if (gh >= 56) gh -= 56;
          int gw = ww * 4 + tx + 2; if (gw >= 56) gw -= 56;
          dst = ((((size_t)b * 16 + gd) * 56 + gh) * 56 + gw) * 256
                + n0 + colf;
        } else {
          dst = (size_t)grow * 256 + n0 + colf;
        }
        const f32x4 r = *(const f32x4*)(resid + dst);
        val = val + r;
        *(f32x4*)(out + dst) = val;
      }
    }
  }
}

// ---------------------------------------------------------------------------
// Windowed attention. grid = 1568*2 blocks; 4 waves, 1 head/wave.
__global__ __launch_bounds__(256) void attn_k(
    const short* __restrict__ qkv, const float* __restrict__ rpb,
    short* __restrict__ aout) {
  __shared__ short Plds[4 * 64 * 80];
  const int tid = threadIdx.x;
  const int wave = tid >> 6, lane = tid & 63;
  const int quad = lane >> 4, l15 = lane & 15;
  const int win = blockIdx.x >> 1;
  const int h = ((blockIdx.x & 1) << 2) + wave;
  const int wi = win % 784;
  const int wd = wi / 196, wh = (wi / 14) % 14, ww = wi % 14;
  const short* base = qkv + (size_t)win * (64 * 768);

  bf16x8 qf[4], kf[4];
#pragma unroll
  for (int t = 0; t < 4; ++t) {
    const short* qp = base + (size_t)(t * 16 + l15) * 768 + h * 32 + quad * 8;
    qf[t] = *(const bf16x8*)qp;
    kf[t] = *(const bf16x8*)(qp + 256);
  }
  f32x4 S[4][4] = {};
#pragma unroll
  for (int mt = 0; mt < 4; ++mt)
#pragma unroll
    for (int nt = 0; nt < 4; ++nt)
      S[mt][nt] = MFMA16(qf[mt], kf[nt], S[mt][nt], 0, 0, 0);

  const bool bd = (wd == 3), bh = (wh == 13), bw = (ww == 13);
  const int yc = l15 >> 2, xc = l15 & 3;
  int labc[4];
#pragma unroll
  for (int nt = 0; nt < 4; ++nt) {
    const int rd = bd ? (nt < 2 ? 1 : 2) : 0;
    const int rh = bh ? (yc < 2 ? 1 : 2) : 0;
    const int rw = bw ? (xc < 2 ? 1 : 2) : 0;
    labc[nt] = rd * 9 + rh * 3 + rw;
  }
  const float scale = 0.17677669529663687f;   // 32^-0.5
#pragma unroll
  for (int mt = 0; mt < 4; ++mt) {
    const int rdr = bd ? (mt < 2 ? 1 : 2) : 0;
    const int rhr = bh ? (quad < 2 ? 1 : 2) : 0;
#pragma unroll
    for (int reg = 0; reg < 4; ++reg) {
      const int rwr = bw ? (reg < 2 ? 1 : 2) : 0;
      const int labr = rdr * 9 + rhr * 3 + rwr;
      float sc[4];
#pragma unroll
      for (int nt = 0; nt < 4; ++nt) {
        const int rpi = (mt - nt + 3) * 49 + (quad - yc + 3) * 7 + (reg - xc + 3);
        const float bias = rpb[rpi * 8 + h];
        const float mv = (labr == labc[nt]) ? 0.f : -100.f;
        sc[nt] = S[mt][nt][reg] * scale + bias + mv;
      }
      float mx = fmaxf(fmaxf(sc[0], sc[1]), fmaxf(sc[2], sc[3]));
      mx = fmaxf(mx, __shfl_xor(mx, 1));
      mx = fmaxf(mx, __shfl_xor(mx, 2));
      mx = fmaxf(mx, __shfl_xor(mx, 4));
      mx = fmaxf(mx, __shfl_xor(mx, 8));
      float p[4], sum = 0.f;
#pragma unroll
      for (int nt = 0; nt < 4; ++nt) { p[nt] = __expf(sc[nt] - mx); sum += p[nt]; }
      sum += __shfl_xor(sum, 1);
      sum += __shfl_xor(sum, 2);
      sum += __shfl_xor(sum, 4);
      sum += __shfl_xor(sum, 8);
      const float inv = 1.f / sum;
      const int r = mt * 16 + quad * 4 + reg;
#pragma unroll
      for (int nt = 0; nt < 4; ++nt)
        Plds[(wave * 64 + r) * 80 + nt * 16 + l15] = f2bf(p[nt] * inv);
    }
  }

  bf16x8 vf[2][2];
#pragma unroll
  for (int kt = 0; kt < 2; ++kt)
#pragma unroll
    for (int n2 = 0; n2 < 2; ++n2)
#pragma unroll
      for (int j = 0; j < 8; ++j)
        vf[kt][n2][j] =
            base[(size_t)(kt * 32 + quad * 8 + j) * 768 + 512 + h * 32 + n2 * 16 + l15];

  f32x4 O[4][2] = {};
#pragma unroll
  for (int mt = 0; mt < 4; ++mt) {
    const short* pr = &Plds[(wave * 64 + mt * 16 + l15) * 80 + quad * 8];
    const bf16x8 pa0 = *(const bf16x8*)pr;
    const bf16x8 pa1 = *(const bf16x8*)(pr + 32);
#pragma unroll
    for (int n2 = 0; n2 < 2; ++n2) {
      O[mt][n2] = MFMA16(pa0, vf[0][n2], O[mt][n2], 0, 0, 0);
      O[mt][n2] = MFMA16(pa1, vf[1][n2], O[mt][n2], 0, 0, 0);
    }
  }
#pragma unroll
  for (int mt = 0; mt < 4; ++mt)
#pragma unroll
    for (int n2 = 0; n2 < 2; ++n2)
#pragma unroll
      for (int reg = 0; reg < 4; ++reg) {
        const int tok = mt * 16 + quad * 4 + reg;
        aout[((size_t)win * 64 + tok) * 256 + h * 32 + n2 * 16 + l15] =
            f2bf(O[mt][n2][reg]);
      }
}

// ---------------------------------------------------------------------------
extern "C" void kernel_launch(void* const* d_in, const int* in_sizes, int n_in,
                              void* d_out, int out_size, void* d_ws,
                              size_t ws_size, hipStream_t stream) {
  const float* x      = (const float*)d_in[0];
  const float* n1g    = (const float*)d_in[1];
  const float* n1b    = (const float*)d_in[2];
  const float* qkv_w  = (const float*)d_in[3];
  const float* qkv_b  = (const float*)d_in[4];
  const float* proj_w = (const float*)d_in[5];
  const float* proj_b = (const float*)d_in[6];
  const float* rpb    = (const float*)d_in[7];
  const float* n2g    = (const float*)d_in[8];
  const float* n2b    = (const float*)d_in[9];
  const float* fc1_w  = (const float*)d_in[10];
  const float* fc1_b  = (const float*)d_in[11];
  const float* fc2_w  = (const float*)d_in[12];
  const float* fc2_b  = (const float*)d_in[13];

  char* ws = (char*)d_ws;
  short* wt_qkv  = (short*)(ws + 0);          //     393,216 B
  short* wt_proj = (short*)(ws + 393216);     //     131,072 B
  short* wt_fc1  = (short*)(ws + 524288);     //     524,288 B
  short* wt_fc2  = (short*)(ws + 1048576);    //     524,288 B
  short* bufS    = (short*)(ws + 1572864);    //  51,380,224 B (xw/ao/yn)
  short* bufL    = (short*)(ws + 52953088);   // 205,520,896 B (qkv/h1)
  // total 258,473,984 B
  float* x1      = (float*)d_out;             // x1 lives in d_out (f32)

  transpose_all_k<<<3072, 256, 0, stream>>>(qkv_w, proj_w, fc1_w, fc2_w,
                                            wt_qkv, wt_proj, wt_fc1, wt_fc2);
  ln1_part_k<<<25088, 256, 0, stream>>>(x, n1g, n1b, bufS);
  gemm_k<0><<<dim3(6, 784), 256, 0, stream>>>(bufS, wt_qkv, qkv_b, nullptr,
                                              bufL, 768, 256);
  attn_k<<<3136, 256, 0, stream>>>(bufL, rpb, bufS);
  gemm_k<2><<<dim3(2, 784), 256, 0, stream>>>(bufS, wt_proj, proj_b, x,
                                              x1, 256, 256);
  ln2_k<<<25088, 256, 0, stream>>>(x1, n2g, n2b, bufS);
  gemm_k<1><<<dim3(8, 784), 256, 0, stream>>>(bufS, wt_fc1, fc1_b, nullptr,
                                              bufL, 1024, 256);
  gemm_k<3><<<dim3(2, 784), 256, 0, stream>>>(bufL, wt_fc2, fc2_b, x1,
                                              x1, 256, 1024);
}